// Round 2
// baseline (323.514 us; speedup 1.0000x reference)
//
#include <hip/hip_runtime.h>
#include <hip/hip_fp16.h>
#include <math.h>

typedef _Float16 f16;
typedef _Float16 f16x8 __attribute__((ext_vector_type(8)));
typedef _Float16 f16x4 __attribute__((ext_vector_type(4)));
typedef float    f32x4 __attribute__((ext_vector_type(4)));

#define MFMA16(a,b,c) __builtin_amdgcn_mfma_f32_16x16x32_f16(a, b, c, 0, 0, 0)

// log2-domain masked-fill sentinel (any consistent constant; exp2(x - x) = 1
// reproduces the reference's uniform-softmax behavior for fully-masked rows).
#define MASKNEG (-6.0e9f)
#define LOG2E   1.44269504088896f

// ---------------------------------------------------------------------------
// Kernel 1: QKV projection.  out[m,c] = sum_k x[m,k] * W[c,k] + b[c]
// x: [8192,512] f32.  Q,K written natural f16 [8192][512]; V written
// transposed f16 [(h*4+b)*64+d][2048] for the attention PV step.
// Tile 128x64, 4 waves (2x2), BK=32 (one f16 MFMA K-step).
// ---------------------------------------------------------------------------
__global__ __launch_bounds__(256) void qkv_gemm(
    const float* __restrict__ x,
    const float* __restrict__ Wq, const float* __restrict__ bq,
    const float* __restrict__ Wk, const float* __restrict__ bk,
    const float* __restrict__ Wv, const float* __restrict__ bv,
    f16* __restrict__ Qws, f16* __restrict__ Kws, f16* __restrict__ Vt)
{
    __shared__ f16 Al[128 * 48];   // stride 48 f16 = 96B (16B aligned rows)
    __shared__ f16 Wl[64 * 48];

    const int tid = threadIdx.x;
    const int bx  = blockIdx.x;          // 0..23 (3 weights x 8 n-tiles)
    const int m0  = blockIdx.y * 128;
    const int widx = bx >> 3;            // 0=Q 1=K 2=V
    const int n0   = (bx & 7) * 64;

    const float* W    = (widx == 0) ? Wq : (widx == 1) ? Wk : Wv;
    const float* bias = (widx == 0) ? bq : (widx == 1) ? bk : bv;

    const int wid = tid >> 6, lane = tid & 63;
    const int g = lane >> 4, c = lane & 15;
    const int wm = (wid >> 1) * 64, wn = (wid & 1) * 32;

    const int sr = tid >> 3, sc = tid & 7;   // staging: 32 rows x 8 float4-chunks

    f32x4 acc[4][2] = {};

    for (int kk = 0; kk < 512; kk += 32) {
        __syncthreads();
        #pragma unroll
        for (int rr = 0; rr < 4; ++rr) {            // A: 128 rows x 32 k
            int row = sr + rr * 32;
            float4 v = *(const float4*)&x[(size_t)(m0 + row) * 512 + kk + sc * 4];
            f16x4 h4 = {(f16)v.x, (f16)v.y, (f16)v.z, (f16)v.w};
            *(f16x4*)&Al[row * 48 + sc * 4] = h4;
        }
        #pragma unroll
        for (int rr = 0; rr < 2; ++rr) {            // W: 64 rows x 32 k
            int row = sr + rr * 32;
            float4 v = *(const float4*)&W[(size_t)(n0 + row) * 512 + kk + sc * 4];
            f16x4 h4 = {(f16)v.x, (f16)v.y, (f16)v.z, (f16)v.w};
            *(f16x4*)&Wl[row * 48 + sc * 4] = h4;
        }
        __syncthreads();

        // B-frag: lane -> W[n=c, k=g*8+j] (natural [n][k] LDS rows)
        f16x8 b0 = *(const f16x8*)&Wl[(wn +  0 + c) * 48 + g * 8];
        f16x8 b1 = *(const f16x8*)&Wl[(wn + 16 + c) * 48 + g * 8];
        #pragma unroll
        for (int mf = 0; mf < 4; ++mf) {
            f16x8 a = *(const f16x8*)&Al[(wm + mf * 16 + c) * 48 + g * 8];
            acc[mf][0] = MFMA16(a, b0, acc[mf][0]);
            acc[mf][1] = MFMA16(a, b1, acc[mf][1]);
        }
    }

    // Epilogue. C/D layout: col = c (lane&15), row = g*4 + reg.
    #pragma unroll
    for (int nf = 0; nf < 2; ++nf) {
        int cc = n0 + wn + nf * 16 + c;      // output channel within this matrix
        float bval = bias[cc];
        #pragma unroll
        for (int mf = 0; mf < 4; ++mf) {
            if (widx < 2) {
                f16* outp = (widx == 0) ? Qws : Kws;
                #pragma unroll
                for (int r = 0; r < 4; ++r) {
                    int mrow = m0 + wm + mf * 16 + g * 4 + r;
                    outp[(size_t)mrow * 512 + cc] = (f16)(acc[mf][nf][r] + bval);
                }
            } else {
                // V transposed: row = n*64+d, col = t  (n = h*4+b)
                int h  = n0 >> 6;
                int d  = wn + nf * 16 + c;
                int t0 = m0 + wm + mf * 16 + g * 4;    // global m, mult of 4
                int b  = t0 >> 11;
                int ts = t0 & 2047;
                int nn = h * 4 + b;
                f16x4 pk = {(f16)(acc[mf][nf][0] + bval), (f16)(acc[mf][nf][1] + bval),
                            (f16)(acc[mf][nf][2] + bval), (f16)(acc[mf][nf][3] + bval)};
                *(f16x4*)&Vt[((size_t)(nn * 64 + d)) * 2048 + ts] = pk;
            }
        }
    }
}

// ---------------------------------------------------------------------------
// Kernel 1b: per-(n,d) sum of V over t, for the fully-masked-row override.
// Vsum[row] = sum_t Vt[row][t], row = n*64+d.  One wave per row.
// ---------------------------------------------------------------------------
__global__ __launch_bounds__(256) void vsum_kernel(
    const f16* __restrict__ Vt, float* __restrict__ Vsum)
{
    const int row  = blockIdx.x * 4 + (threadIdx.x >> 6);
    const int lane = threadIdx.x & 63;
    const f16* p = Vt + (size_t)row * 2048;
    float s = 0.f;
    #pragma unroll
    for (int i = 0; i < 4; ++i) {
        f16x8 v = *(const f16x8*)&p[i * 512 + lane * 8];
        #pragma unroll
        for (int j = 0; j < 8; ++j) s += (float)v[j];
    }
    #pragma unroll
    for (int off = 1; off < 64; off <<= 1) s += __shfl_xor(s, off, 64);
    if (lane == 0) Vsum[row] = s;
}

// ---------------------------------------------------------------------------
// Kernel 2: fused attention.  One block = one (n = h*4+b) x 64 q-rows.
// 4 waves x 16 q-rows.  Loops 32 tiles of 64 keys:
//   S = Q Kt (MFMA) -> write pre_score (unmasked, scaled, nontemporal) for ALL
//   tiles; softmax+PV only for tiles kt <= qt (block-uniform causal skip;
//   dead tiles contribute exp(NEG-m)=0 unless the row is fully masked, which
//   the Vsum/2048 epilogue override reproduces exactly).
// ---------------------------------------------------------------------------
__global__ __launch_bounds__(256) void attn_kernel(
    const f16* __restrict__ Qws, const f16* __restrict__ Kws,
    const f16* __restrict__ Vt,  const int* __restrict__ pmask,
    const float* __restrict__ Vsum,
    float* __restrict__ pre_score, f16* __restrict__ attn_out)
{
    __shared__ f16 Kl[64 * 72];        // [t][d], stride 72 f16 = 144B
    __shared__ f16 Vl[64 * 72];        // [d][t]
    __shared__ f16 Pl[4][16 * 72];     // per-wave [q][t]

    const int tid = threadIdx.x;
    const int wid = tid >> 6, lane = tid & 63;
    const int g = lane >> 4, c = lane & 15;
    const int qt = blockIdx.x;         // 0..31 (64 q-rows each)
    const int n  = blockIdx.y;         // 0..31  (= h*4 + b)
    const int h = n >> 2, b = n & 3;
    const int pmrow = n >> 3;          // the reference's ordering quirk
    const int q0w = qt * 64 + wid * 16;

    // Q fragments in registers (A-op: lane -> Q[q=c, k=g*8+j])
    f16x8 qf[2];
    #pragma unroll
    for (int ks = 0; ks < 2; ++ks)
        qf[ks] = *(const f16x8*)
            &Qws[(size_t)(b * 2048 + q0w + c) * 512 + h * 64 + ks * 32 + g * 8];

    f32x4 o[4] = {};
    float mrow[4], lrow[4];
    #pragma unroll
    for (int r = 0; r < 4; ++r) { mrow[r] = -INFINITY; lrow[r] = 0.0f; }

    const int sr = tid >> 3, sc = tid & 7;
    const int* pmp = pmask + pmrow * 2048;
    // pre_score base for this lane's 4 rows (q0w+g*4 .. +3)
    float* prow = pre_score + ((size_t)n * 2048 + q0w + g * 4) * 2048;

    for (int kt = 0; kt < 32; ++kt) {
        __syncthreads();
        #pragma unroll
        for (int rr = 0; rr < 2; ++rr) {
            int row = sr + rr * 32;
            *(uint4*)&Kl[row * 72 + sc * 8] =
                *(const uint4*)&Kws[(size_t)(b * 2048 + kt * 64 + row) * 512 + h * 64 + sc * 8];
        }
        if (kt <= qt) {
            #pragma unroll
            for (int rr = 0; rr < 2; ++rr) {
                int row = sr + rr * 32;
                *(uint4*)&Vl[row * 72 + sc * 8] =
                    *(const uint4*)&Vt[(size_t)(n * 64 + row) * 2048 + kt * 64 + sc * 8];
            }
        }
        __syncthreads();

        // ---- S = Q K^T (always: pre_score is mandatory everywhere) -------
        f32x4 s[4] = {};
        #pragma unroll
        for (int nf = 0; nf < 4; ++nf) {
            #pragma unroll
            for (int ks = 0; ks < 2; ++ks) {
                f16x8 kf = *(const f16x8*)&Kl[(nf * 16 + c) * 72 + ks * 32 + g * 8];
                s[nf] = MFMA16(qf[ks], kf, s[nf]);
            }
        }

        // ---- emit pre_score (unmasked, scaled) ---------------------------
        #pragma unroll
        for (int nf = 0; nf < 4; ++nf) {
            int tg = kt * 64 + nf * 16 + c;
            #pragma unroll
            for (int r = 0; r < 4; ++r)
                __builtin_nontemporal_store(s[nf][r] * 0.125f,
                                            &prow[(size_t)r * 2048 + tg]);
        }

        // ---- softmax + PV, only for causally-live tiles (block-uniform) --
        if (kt <= qt) {
            float sl[4][4];
            #pragma unroll
            for (int nf = 0; nf < 4; ++nf) {
                int tg  = kt * 64 + nf * 16 + c;
                int pmv = pmp[tg];
                #pragma unroll
                for (int r = 0; r < 4; ++r) {
                    int srow = q0w + g * 4 + r;
                    sl[nf][r] = (tg <= srow && pmv != 0)
                              ? s[nf][r] * (0.125f * LOG2E) : MASKNEG;
                }
            }
            float alpha[4];
            #pragma unroll
            for (int r = 0; r < 4; ++r) {
                float rm = fmaxf(fmaxf(sl[0][r], sl[1][r]),
                                 fmaxf(sl[2][r], sl[3][r]));
                rm = fmaxf(rm, __shfl_xor(rm, 1, 64));
                rm = fmaxf(rm, __shfl_xor(rm, 2, 64));
                rm = fmaxf(rm, __shfl_xor(rm, 4, 64));
                rm = fmaxf(rm, __shfl_xor(rm, 8, 64));
                float mn = fmaxf(mrow[r], rm);
                alpha[r] = exp2f(mrow[r] - mn);   // exp2(-inf)=0 on first tile
                mrow[r] = mn;
            }
            float rs[4] = {0.f, 0.f, 0.f, 0.f};
            #pragma unroll
            for (int nf = 0; nf < 4; ++nf)
                #pragma unroll
                for (int r = 0; r < 4; ++r) {
                    float p = exp2f(sl[nf][r] - mrow[r]);
                    rs[r] += p;
                    Pl[wid][(g * 4 + r) * 72 + nf * 16 + c] = (f16)p;
                }
            #pragma unroll
            for (int r = 0; r < 4; ++r) {
                float t = rs[r];
                t += __shfl_xor(t, 1, 64);
                t += __shfl_xor(t, 2, 64);
                t += __shfl_xor(t, 4, 64);
                t += __shfl_xor(t, 8, 64);
                lrow[r] = lrow[r] * alpha[r] + t;
                #pragma unroll
                for (int dn = 0; dn < 4; ++dn) o[dn][r] *= alpha[r];
            }
            // Pl is wave-private: wave-local drain orders write->read.
            asm volatile("s_waitcnt lgkmcnt(0)" ::: "memory");

            #pragma unroll
            for (int ks = 0; ks < 2; ++ks) {
                f16x8 pa = *(const f16x8*)&Pl[wid][c * 72 + ks * 32 + g * 8];
                #pragma unroll
                for (int dn = 0; dn < 4; ++dn) {
                    f16x8 vb = *(const f16x8*)&Vl[(dn * 16 + c) * 72 + ks * 32 + g * 8];
                    o[dn] = MFMA16(pa, vb, o[dn]);
                }
            }
        }
    }

    // ---- epilogue: O /= l (or uniform-row override), write heads f16 -----
    #pragma unroll
    for (int r = 0; r < 4; ++r) {
        int srow = q0w + g * 4 + r;
        bool dead = (mrow[r] == MASKNEG);   // no valid key anywhere in row
        float inv_l = dead ? 0.f : 1.0f / lrow[r];
        #pragma unroll
        for (int dn = 0; dn < 4; ++dn) {
            float val = dead ? Vsum[n * 64 + dn * 16 + c] * (1.0f / 2048.0f)
                             : o[dn][r] * inv_l;
            attn_out[(size_t)(b * 2048 + srow) * 512 + h * 64 + dn * 16 + c] = (f16)val;
        }
    }
}

// ---------------------------------------------------------------------------
// Kernel 3: output projection.  out[m,n] = sum_c heads[m,c]*Wo[n,c] + bo[n]
// heads f16 [8192][512], Wo f32 [512][512], out f32 -> d_out[0:4194304).
// ---------------------------------------------------------------------------
__global__ __launch_bounds__(256) void out_gemm(
    const f16* __restrict__ Aattn, const float* __restrict__ Wo,
    const float* __restrict__ bo, float* __restrict__ outp)
{
    __shared__ f16 Al[128 * 48];
    __shared__ f16 Wl[64 * 48];

    const int tid = threadIdx.x;
    const int n0 = blockIdx.x * 64;
    const int m0 = blockIdx.y * 128;
    const int wid = tid >> 6, lane = tid & 63;
    const int g = lane >> 4, c = lane & 15;
    const int wm = (wid >> 1) * 64, wn = (wid & 1) * 32;

    const int sr4 = tid >> 2, sc4 = tid & 3;   // A: 64 rows x 4 16B-chunks
    const int sr8 = tid >> 3, sc8 = tid & 7;   // W: 32 rows x 8 float4-chunks

    f32x4 acc[4][2] = {};

    for (int kk = 0; kk < 512; kk += 32) {
        __syncthreads();
        #pragma unroll
        for (int rr = 0; rr < 2; ++rr) {
            int row = sr4 + rr * 64;
            *(uint4*)&Al[row * 48 + sc4 * 8] =
                *(const uint4*)&Aattn[(size_t)(m0 + row) * 512 + kk + sc4 * 8];
        }
        #pragma unroll
        for (int rr = 0; rr < 2; ++rr) {
            int row = sr8 + rr * 32;
            float4 v = *(const float4*)&Wo[(size_t)(n0 + row) * 512 + kk + sc8 * 4];
            f16x4 h4 = {(f16)v.x, (f16)v.y, (f16)v.z, (f16)v.w};
            *(f16x4*)&Wl[row * 48 + sc8 * 4] = h4;
        }
        __syncthreads();

        f16x8 b0 = *(const f16x8*)&Wl[(wn +  0 + c) * 48 + g * 8];
        f16x8 b1 = *(const f16x8*)&Wl[(wn + 16 + c) * 48 + g * 8];
        #pragma unroll
        for (int mf = 0; mf < 4; ++mf) {
            f16x8 a = *(const f16x8*)&Al[(wm + mf * 16 + c) * 48 + g * 8];
            acc[mf][0] = MFMA16(a, b0, acc[mf][0]);
            acc[mf][1] = MFMA16(a, b1, acc[mf][1]);
        }
    }

    #pragma unroll
    for (int nf = 0; nf < 2; ++nf) {
        int cc = n0 + wn + nf * 16 + c;
        float bval = bo[cc];
        #pragma unroll
        for (int mf = 0; mf < 4; ++mf)
            #pragma unroll
            for (int r = 0; r < 4; ++r)
                outp[(size_t)(m0 + wm + mf * 16 + g * 4 + r) * 512 + cc] =
                    acc[mf][nf][r] + bval;
    }
}

// ---------------------------------------------------------------------------
extern "C" void kernel_launch(void* const* d_in, const int* in_sizes, int n_in,
                              void* d_out, int out_size, void* d_ws, size_t ws_size,
                              hipStream_t stream)
{
    (void)in_sizes; (void)n_in; (void)out_size; (void)ws_size;

    const float* x  = (const float*)d_in[0];
    const int*   pm = (const int*)  d_in[1];
    const float* Wq = (const float*)d_in[2];
    const float* bq = (const float*)d_in[3];
    const float* Wk = (const float*)d_in[4];
    const float* bk = (const float*)d_in[5];
    const float* Wv = (const float*)d_in[6];
    const float* bv = (const float*)d_in[7];
    const float* Wo = (const float*)d_in[8];
    const float* bo = (const float*)d_in[9];

    float* out = (float*)d_out;                 // [4][2048][512]
    float* pre = out + (size_t)4 * 2048 * 512;  // [32][2048][2048]

    f16*   Qws  = (f16*)d_ws;                   //  8 MiB
    f16*   Kws  = Qws + (size_t)8192 * 512;     //  8 MiB
    f16*   Vt   = Kws + (size_t)8192 * 512;     //  8 MiB (transposed V)
    f16*   Aat  = Vt  + (size_t)2048 * 2048;    //  8 MiB (heads)
    float* Vsum = (float*)(Aat + (size_t)8192 * 512);  // 8 KiB

    qkv_gemm   <<<dim3(24, 64), 256, 0, stream>>>(x, Wq, bq, Wk, bk, Wv, bv, Qws, Kws, Vt);
    vsum_kernel<<<dim3(512),    256, 0, stream>>>(Vt, Vsum);
    attn_kernel<<<dim3(32, 32), 256, 0, stream>>>(Qws, Kws, Vt, pm, Vsum, pre, Aat);
    out_gemm   <<<dim3(8, 64),  256, 0, stream>>>(Aat, Wo, bo, out);
}